// Round 11
// baseline (188.689 us; speedup 1.0000x reference)
//
#include <hip/hip_runtime.h>
#include <cmath>

constexpr int BB = 4, CC = 64, HH = 256, WW = 256;
constexpr int WP = 258;   // padded width: cols -1..256 stored at col+1
constexpr int C2R = 257;  // c2 rows -1..255 stored at r+1

typedef short short8 __attribute__((ext_vector_type(8)));
typedef float f32x4 __attribute__((ext_vector_type(4)));
#define MFMA_BF16 __builtin_amdgcn_mfma_f32_16x16x32_bf16

typedef __attribute__((address_space(1))) const unsigned gptr_t;
typedef __attribute__((address_space(3))) unsigned lptr_t;

union U16x8 { uint4 v; unsigned short h[8]; };
union U16x4 { uint2 v; unsigned short h[4]; };

__device__ inline unsigned short f2bf(float f) {
  unsigned u = __builtin_bit_cast(unsigned, f);
  u += 0x7fffu + ((u >> 16) & 1u);
  return (unsigned short)(u >> 16);
}
__device__ inline unsigned short f2bf_trunc(float f) {
  return (unsigned short)(__builtin_bit_cast(unsigned, f) >> 16);
}
__device__ inline float bf2f(unsigned short h) {
  unsigned u = ((unsigned)h) << 16;
  return __builtin_bit_cast(float, u);
}

// ---------------------------------------------------------------------------
// k_pack: block = half-row (128 px). NCHW fp32 -> col-padded NHWC bf16 +
// fused channel-max -> s. First 18 blocks of b=0 also do the weight pack.
// ---------------------------------------------------------------------------
__global__ __launch_bounds__(256, 4) void k_pack(const float* __restrict__ x,
                                                 const float* __restrict__ Wt,
                                                 float* __restrict__ s,
                                                 unsigned short* __restrict__ xn,
                                                 unsigned short* __restrict__ Wp) {
  __shared__ float tile[CC * 129];
  __shared__ float pmax[2][128];
  const int t = threadIdx.x;
  const int half = blockIdx.x & 1, y = blockIdx.x >> 1, b = blockIdx.y;
  const int px0 = half * 128;
  const int pxl = t & 127, chb = (t >> 7) * 32;

  if (b == 0 && blockIdx.x < 18) {
    int gid = blockIdx.x * 256 + t;  // 4608 total
    int lane = gid & 63, kc = (gid >> 6) & 1, mt = (gid >> 7) & 3, tap = gid >> 9;
    int o = mt * 16 + (lane & 15);
    int kb = kc * 32 + (lane >> 4) * 8;
    int ky = tap / 3, kx = tap % 3;
    U16x8 r;
#pragma unroll
    for (int j = 0; j < 8; ++j)
      r.h[j] = f2bf(Wt[o * 576 + (kb + j) * 9 + ky * 3 + kx]);
    ((uint4*)Wp)[gid] = r.v;
  }

  const float* base = x + (size_t)b * CC * HH * WW + (size_t)y * WW + px0 + pxl;
  float m = -1e30f;
#pragma unroll 8
  for (int i = 0; i < 32; ++i) {
    float v = base[(size_t)(chb + i) * HH * WW];
    tile[(chb + i) * 129 + pxl] = v;
    m = fmaxf(m, v);
  }
  pmax[t >> 7][pxl] = m;

  uint4* xn4 = (uint4*)xn;
  if (t < 8) {
    int col = half ? (WP - 1) : 0;
    xn4[(((size_t)(b * HH + y) * WP + col) * CC + t * 8) >> 3] =
        make_uint4(0, 0, 0, 0);
  }
  __syncthreads();

  if (t < 128) {
    float mm = fmaxf(pmax[0][t], pmax[1][t]);
    s[(b * HH + y) * WW + px0 + t] = 25.0f / fminf(fmaxf(mm, 1.0f), 50.0f);
  }
#pragma unroll
  for (int g = 0; g < 4; ++g) {
    int px = g * 32 + (t >> 3), c8 = t & 7;
    U16x8 r;
#pragma unroll
    for (int j = 0; j < 8; ++j) r.h[j] = f2bf(tile[(c8 * 8 + j) * 129 + px]);
    xn4[(((size_t)(b * HH + y) * WP + px0 + px + 1) * CC + c8 * 8) >> 3] = r.v;
  }
}

// ---------------------------------------------------------------------------
// Conv tile (R6 body + R9 XCD swizzle; verified R10: FETCH at unique-data
// minimum). c2 layout [b][row+1][px][og] (uint2); LDS-transpose epilogue.
// ---------------------------------------------------------------------------
__global__ __launch_bounds__(256, 4) void k_lower(const unsigned short* __restrict__ xn,
                                                  const unsigned short* __restrict__ Wp,
                                                  const float* __restrict__ s,
                                                  unsigned short* __restrict__ c2) {
  __shared__ uint4 lds[2112];
  const int t = threadIdx.x;
  const int swz = ((int)blockIdx.x & 7) * 65 + ((int)blockIdx.x >> 3);
  if (swz >= 516) return;  // padding tiles (uniform per block)
  const int ctile = swz & 3, tr = swz >> 2;
  const int b = blockIdx.y;
  const int r0 = tr * 2 - 1;          // out rows r0, r0+1 in [-1, 256]
  const int colBase = ctile * 64;

  const uint4* xn4 = (const uint4*)xn;

  // ---- phase 1: all 9 per-thread s-loads in flight together
  float sva[9];
#pragma unroll
  for (int j = 0; j < 9; ++j) {
    int idx = j * 256 + t;
    bool act = (j < 8) || (t < 64);
    int rr_ = idx / 528, rem = idx % 528;
    int col_ = rem >> 3;
    int xrow = r0 - 1 + rr_;  // x2 row, [-2..258]
    bool va = act && (xrow >= 0) && (xrow < HH);
    int pxc = min(max(colBase + col_ - 1, 0), WW - 1);
    sva[j] = va ? s[(b * HH + min(max(xrow, 0), HH - 1)) * WW + pxc] : 0.0f;
  }

  // ---- phase 2: gather+blend in 5+4 batches (loads clustered per batch)
#pragma unroll
  for (int h = 0; h < 2; ++h) {
    const int jb = h * 5;
    const int n = h ? 4 : 5;
    uint4 u0[5], u1[5];
    float w0a[5], w1a[5];
    int la[5];
    bool act[5], va[5];
#pragma unroll
    for (int j = 0; j < 5; ++j) {
      if (j >= n) break;
      const int e = jb + j;
      int idx = e * 256 + t;
      act[j] = (e < 8) || (t < 64);
      int rr_ = idx / 528, rem = idx % 528;
      int col_ = rem >> 3, ch_ = rem & 7;
      int xrow = r0 - 1 + rr_;
      va[j] = act[j] && (xrow >= 0) && (xrow < HH);
      la[j] = (rr_ * 66 + col_) * 8 + (ch_ ^ (col_ & 7));
      float ys = (float)xrow - sva[e];
      float fy = floorf(ys);
      float wfr = ys - fy;
      int i0 = (int)fy;
      w0a[j] = (i0 >= 0) ? 1.0f - wfr : 0.0f;
      w1a[j] = (i0 + 1 >= 0) ? wfr : 0.0f;
      int a0 = min(max(i0, 0), HH - 1), a1 = min(max(i0 + 1, 0), HH - 1);
      int o0 = ((b * HH + a0) * WP + colBase + col_) * 8 + ch_;
      int o1 = ((b * HH + a1) * WP + colBase + col_) * 8 + ch_;
      if (va[j]) {
        u0[j] = xn4[o0];
        u1[j] = xn4[o1];
      }
    }
#pragma unroll
    for (int j = 0; j < 5; ++j) {
      if (j >= n) break;
      if (act[j]) {
        uint4 v = make_uint4(0, 0, 0, 0);
        if (va[j]) {
          U16x8 a, bb, rr;
          a.v = u0[j];
          bb.v = u1[j];
#pragma unroll
          for (int k = 0; k < 8; ++k)
            rr.h[k] = f2bf_trunc(w0a[j] * bf2f(a.h[k]) + w1a[j] * bf2f(bb.h[k]));
          v = rr.v;
        }
        lds[la[j]] = v;
      }
    }
  }

  const int lane = t & 63, w = t >> 6;
  const int ow = w & 1, ch2 = w >> 1;
  const int quad = lane >> 4, l15 = lane & 15;
  const uint4* wp4 = (const uint4*)Wp;
  __syncthreads();

  f32x4 acc[2][2][2];  // [pt][rr][ct]
#pragma unroll
  for (int pt = 0; pt < 2; ++pt)
#pragma unroll
    for (int rr = 0; rr < 2; ++rr)
#pragma unroll
      for (int ct = 0; ct < 2; ++ct) acc[pt][rr][ct] = {0.f, 0.f, 0.f, 0.f};

#pragma unroll 1
  for (int kc = 0; kc < 2; ++kc) {
    short8 wf[9][2];
#pragma unroll
    for (int tap = 0; tap < 9; ++tap)
#pragma unroll
      for (int ct = 0; ct < 2; ++ct)
        wf[tap][ct] = __builtin_bit_cast(
            short8, wp4[((tap * 4 + (ow * 2 + ct)) * 2 + kc) * 64 + lane]);
#pragma unroll
    for (int pt = 0; pt < 2; ++pt) {
#pragma unroll
      for (int ir = 0; ir < 4; ++ir) {
#pragma unroll
        for (int kx = 0; kx < 3; ++kx) {
          int col = ch2 * 32 + pt * 16 + l15 + kx;
          short8 xf = __builtin_bit_cast(
              short8, lds[(ir * 66 + col) * 8 + ((kc * 4 + quad) ^ (col & 7))]);
          if (ir <= 2) {
#pragma unroll
            for (int ct = 0; ct < 2; ++ct)
              acc[pt][0][ct] = MFMA_BF16(wf[ir * 3 + kx][ct], xf, acc[pt][0][ct], 0, 0, 0);
          }
          if (ir >= 1) {
#pragma unroll
            for (int ct = 0; ct < 2; ++ct)
              acc[pt][1][ct] = MFMA_BF16(wf[(ir - 1) * 3 + kx][ct], xf, acc[pt][1][ct], 0, 0, 0);
          }
        }
      }
    }
  }

  // ---- LDS-transpose epilogue: full-line c2 stores in [row][px][og] layout
  __syncthreads();  // all MFMA LDS reads complete before reuse
  uint2* sb = (uint2*)lds;  // [2][64] (row,px) units, stride 18 uint2 (16B-aligned)
#pragma unroll
  for (int pt = 0; pt < 2; ++pt) {
    int pxl = ch2 * 32 + pt * 16 + l15;  // block-local px 0..63
#pragma unroll
    for (int rr = 0; rr < 2; ++rr) {
#pragma unroll
      for (int ct = 0; ct < 2; ++ct) {
        f32x4 A = acc[pt][rr][ct];
        int og = (ow * 2 + ct) * 4 + quad;
        unsigned short h0 = f2bf(A[0]), h1 = f2bf(A[1]), h2 = f2bf(A[2]), h3 = f2bf(A[3]);
        sb[(rr * 64 + pxl) * 18 + og] =
            make_uint2((unsigned)h0 | ((unsigned)h1 << 16),
                       (unsigned)h2 | ((unsigned)h3 << 16));
      }
    }
  }
  __syncthreads();
  {
    uint2* c2u = (uint2*)c2;
    int h = t & 1, u = t >> 1;        // u = rr*64 + pxl
    int rr = u >> 6, pxl = u & 63;
    int r = r0 + rr;                  // r = -1 is REAL data (c2 row 0)
    if (r < 256) {
      const uint2* srcp = sb + u * 18 + h * 8;
      uint4 q0 = *(const uint4*)(srcp + 0);
      uint4 q1 = *(const uint4*)(srcp + 2);
      uint4 q2 = *(const uint4*)(srcp + 4);
      uint4 q3 = *(const uint4*)(srcp + 6);
      uint4* dst = (uint4*)(c2u + ((((size_t)(b * C2R + (r + 1)) * WW) + colBase + pxl) << 4) + h * 8);
      dst[0] = q0; dst[1] = q1; dst[2] = q2; dst[3] = q3;
    }
  }
}

// ---------------------------------------------------------------------------
// k_final (R10 body + R11 gather hoist). The epilogue c2 gather's ADDRESSES
// depend only on sv_e (start of kernel), and its VALUES on the previous
// kernel — independent of this block's MFMA. R10 showed pipes running in
// series (VALU 11 + MFMA 7 + LDS 6 + HBM 16 ~= 40 ~= 44 measured). Hoisting
// the 16 per-thread gather loads to the top puts their ~500cy chains under
// the stage+MFMA span, deleting one serial phase. +32 VGPR (56->~95 < 128).
// ---------------------------------------------------------------------------
__global__ __launch_bounds__(256, 4) void k_final(const unsigned short* __restrict__ xn,
                                                  const unsigned short* __restrict__ Wp,
                                                  const float* __restrict__ s,
                                                  const unsigned short* __restrict__ c2,
                                                  float* __restrict__ out) {
  __shared__ uint4 lds[2112];
  const int t = threadIdx.x;
  const int swz = ((int)blockIdx.x & 7) * 64 + ((int)blockIdx.x >> 3);
  const int ctile = swz & 3, tr = swz >> 2;
  const int b = blockIdx.y;
  const int y0 = tr * 2;
  const int colBase = ctile * 64;

  const int lane = t & 63, w = t >> 6;
  const int ow = w & 1, ch2 = w >> 1;
  const int quad = lane >> 4, l15 = lane & 15;
  const uint4* src4 = (const uint4*)xn;
  const uint4* wp4 = (const uint4*)Wp;
  const uint2* c2u = (const uint2*)c2;

  // ---- hoisted epilogue: s-loads, weights, and ALL 16 c2 gather loads
  float sv_e[2][2];
#pragma unroll
  for (int pt = 0; pt < 2; ++pt)
#pragma unroll
    for (int rr = 0; rr < 2; ++rr)
      sv_e[pt][rr] =
          s[(b * HH + (y0 + rr)) * WW + (colBase + ch2 * 32 + pt * 16 + l15)];

  float lw0a[2][2], lw1a[2][2];
  U16x4 v0a[2][2][2], v1a[2][2][2];
#pragma unroll
  for (int pt = 0; pt < 2; ++pt) {
    int px = colBase + ch2 * 32 + pt * 16 + l15;
#pragma unroll
    for (int rr = 0; rr < 2; ++rr) {
      int y = y0 + rr;
      float sv = sv_e[pt][rr];
      float ys = (float)y - sv;
      float fy = floorf(ys);
      float wfr = ys - fy;
      int i0 = (int)fy;
      lw0a[pt][rr] = (i0 + 1 >= 0 && i0 + 1 <= HH) ? 1.0f - wfr : 0.0f;
      lw1a[pt][rr] = (i0 + 2 >= 0 && i0 + 2 <= HH) ? wfr : 0.0f;
      int a0 = min(max(i0 + 1, 0), HH);
      int a1 = min(max(i0 + 2, 0), HH);
#pragma unroll
      for (int ct = 0; ct < 2; ++ct) {
        int og = (ow * 2 + ct) * 4 + quad;
        // c2 layout: [b][row][px][og] — values written by k_lower (prev kernel)
        v0a[pt][rr][ct].v = c2u[(((size_t)(b * C2R + a0) * WW + px) << 4) + og];
        v1a[pt][rr][ct].v = c2u[(((size_t)(b * C2R + a1) * WW + px) << 4) + og];
      }
    }
  }

  if (tr > 0 && tr < 127) {
    // fast path: 9 async direct-to-LDS loads per thread, all in flight
#pragma unroll
    for (int i = 0; i < 8; ++i) {
      int idx = i * 256 + t;
      int rr_ = idx / 528, rem = idx % 528;
      int col_ = rem >> 3, ch_ = rem & 7;
      int xrow = y0 - 1 + rr_;  // in [1,254], always valid here
      size_t srcIdx =
          ((size_t)(b * HH + xrow) * WP + colBase + col_) * 8 + (ch_ ^ (col_ & 7));
      __builtin_amdgcn_global_load_lds((gptr_t*)(const void*)(src4 + srcIdx),
                                       (lptr_t*)(void*)&lds[i * 256 + (t & 192)],
                                       16, 0, 0);
    }
    if (t < 64) {  // wave-uniform tail: elements 2048..2111
      int idx = 2048 + t;
      int rr_ = idx / 528, rem = idx % 528;
      int col_ = rem >> 3, ch_ = rem & 7;
      int xrow = y0 - 1 + rr_;
      size_t srcIdx =
          ((size_t)(b * HH + xrow) * WP + colBase + col_) * 8 + (ch_ ^ (col_ & 7));
      __builtin_amdgcn_global_load_lds((gptr_t*)(const void*)(src4 + srcIdx),
                                       (lptr_t*)(void*)&lds[2048],
                                       16, 0, 0);
    }
  } else {
    // boundary path: register staging with zero-fill
#pragma unroll
    for (int i = 0; i < 9; ++i) {
      int idx = i * 256 + t;
      if (idx < 2112) {
        int rr_ = idx / 528, rem = idx % 528;
        int col_ = rem >> 3, ch_ = rem & 7;
        int xrow = y0 - 1 + rr_;  // rows y0-1 .. y0+2
        uint4 v = make_uint4(0, 0, 0, 0);
        if (xrow >= 0 && xrow < HH)
          v = src4[((size_t)(b * HH + xrow) * WP + colBase + col_) * 8 + ch_];
        lds[(rr_ * 66 + col_) * 8 + (ch_ ^ (col_ & 7))] = v;
      }
    }
  }
  __syncthreads();

  f32x4 acc[2][2][2];
#pragma unroll
  for (int pt = 0; pt < 2; ++pt)
#pragma unroll
    for (int rr = 0; rr < 2; ++rr)
#pragma unroll
      for (int ct = 0; ct < 2; ++ct) acc[pt][rr][ct] = {0.f, 0.f, 0.f, 0.f};

#pragma unroll 1
  for (int kc = 0; kc < 2; ++kc) {
    short8 wf[9][2];
#pragma unroll
    for (int tap = 0; tap < 9; ++tap)
#pragma unroll
      for (int ct = 0; ct < 2; ++ct)
        wf[tap][ct] = __builtin_bit_cast(
            short8, wp4[((tap * 4 + (ow * 2 + ct)) * 2 + kc) * 64 + lane]);
#pragma unroll
    for (int pt = 0; pt < 2; ++pt) {
#pragma unroll
      for (int ir = 0; ir < 4; ++ir) {
#pragma unroll
        for (int kx = 0; kx < 3; ++kx) {
          int col = ch2 * 32 + pt * 16 + l15 + kx;
          short8 xf = __builtin_bit_cast(
              short8, lds[(ir * 66 + col) * 8 + ((kc * 4 + quad) ^ (col & 7))]);
          if (ir <= 2) {
#pragma unroll
            for (int ct = 0; ct < 2; ++ct)
              acc[pt][0][ct] = MFMA_BF16(wf[ir * 3 + kx][ct], xf, acc[pt][0][ct], 0, 0, 0);
          }
          if (ir >= 1) {
#pragma unroll
            for (int ct = 0; ct < 2; ++ct)
              acc[pt][1][ct] = MFMA_BF16(wf[(ir - 1) * 3 + kx][ct], xf, acc[pt][1][ct], 0, 0, 0);
          }
        }
      }
    }
  }

  // ---- epilogue: min against preloaded gather -> LDS -> full-line out stores
  __syncthreads();             // MFMA LDS reads complete; reuse buffer
  float* lf = (float*)lds;     // 128 units (u=rr*64+c) x 64 dwords = 32 KB
#pragma unroll
  for (int pt = 0; pt < 2; ++pt) {
    int pxl = ch2 * 32 + pt * 16 + l15;
#pragma unroll
    for (int rr = 0; rr < 2; ++rr) {
      float lw0 = lw0a[pt][rr];
      float lw1 = lw1a[pt][rr];
#pragma unroll
      for (int ct = 0; ct < 2; ++ct) {
        f32x4 A = acc[pt][rr][ct];
        int og = (ow * 2 + ct) * 4 + quad;
#pragma unroll
        for (int reg = 0; reg < 4; ++reg) {
          float lower = lw0 * bf2f(v0a[pt][rr][ct].h[reg]) +
                        lw1 * bf2f(v1a[pt][rr][ct].h[reg]);
          int u = rr * 64 + og * 4 + reg;
          // 4-dword XOR swizzle keeps write 2-way-bank-free, read 16B-aligned
          lf[u * 64 + (((pxl >> 2) ^ (u & 15)) << 2) + (pxl & 3)] =
              fminf(A[reg], lower);
        }
      }
    }
  }
  __syncthreads();
#pragma unroll
  for (int j = 0; j < 8; ++j) {
    int u = w * 32 + j * 4 + (lane >> 4);   // wave covers units [32w, 32w+32)
    int c = u & 63, rr = u >> 6;
    int lp = lane & 15;
    const float* srcp = lf + u * 64 + ((lp ^ (u & 15)) << 2);
    float4 q = *(const float4*)srcp;
    *(float4*)(out + ((size_t)(b * CC + c) * HH + (y0 + rr)) * WW + colBase +
               lp * 4) = q;
  }
}

// ---------------------------------------------------------------------------
extern "C" void kernel_launch(void* const* d_in, const int* in_sizes, int n_in,
                              void* d_out, int out_size, void* d_ws, size_t ws_size,
                              hipStream_t stream) {
  const float* x = (const float*)d_in[0];
  const float* Wt = (const float*)d_in[1];
  float* out = (float*)d_out;

  char* ws = (char*)d_ws;
  float* s = (float*)ws;                                   //   1,048,576 B
  unsigned short* Wp = (unsigned short*)(ws + 1048576);    //      73,728 B
  unsigned short* xn = (unsigned short*)(ws + 1122304);    //  33,816,576 B
  unsigned short* c2 = (unsigned short*)(ws + 34938880);   //  33,685,504 B
                                                           // total 68.6 MB
  k_pack<<<dim3(HH * 2, BB), 256, 0, stream>>>(x, Wt, s, xn, Wp);
  k_lower<<<dim3(520, BB), 256, 0, stream>>>(xn, Wp, s, c2);    // 520 = 8*65 (4 pad tiles)
  k_final<<<dim3(512, BB), 256, 0, stream>>>(xn, Wp, s, c2, out);
}

// Round 12
// 180.483 us; speedup vs baseline: 1.0455x; 1.0455x over previous
//
#include <hip/hip_runtime.h>
#include <cmath>

constexpr int BB = 4, CC = 64, HH = 256, WW = 256;
constexpr int WP = 258;   // padded width: cols -1..256 stored at col+1
constexpr int C2R = 257;  // c2 rows -1..255 stored at r+1

typedef short short8 __attribute__((ext_vector_type(8)));
typedef float f32x4 __attribute__((ext_vector_type(4)));
#define MFMA_BF16 __builtin_amdgcn_mfma_f32_16x16x32_bf16

typedef __attribute__((address_space(1))) const unsigned gptr_t;
typedef __attribute__((address_space(3))) unsigned lptr_t;

union U16x8 { uint4 v; unsigned short h[8]; };
union U16x4 { uint2 v; unsigned short h[4]; };

__device__ inline unsigned short f2bf(float f) {
  unsigned u = __builtin_bit_cast(unsigned, f);
  u += 0x7fffu + ((u >> 16) & 1u);
  return (unsigned short)(u >> 16);
}
__device__ inline unsigned short f2bf_trunc(float f) {
  return (unsigned short)(__builtin_bit_cast(unsigned, f) >> 16);
}
__device__ inline float bf2f(unsigned short h) {
  unsigned u = ((unsigned)h) << 16;
  return __builtin_bit_cast(float, u);
}

// ---------------------------------------------------------------------------
// k_pack: block = half-row (128 px). NCHW fp32 -> col-padded NHWC bf16 +
// fused channel-max -> s. First 18 blocks of b=0 also do the weight pack.
// ---------------------------------------------------------------------------
__global__ __launch_bounds__(256, 4) void k_pack(const float* __restrict__ x,
                                                 const float* __restrict__ Wt,
                                                 float* __restrict__ s,
                                                 unsigned short* __restrict__ xn,
                                                 unsigned short* __restrict__ Wp) {
  __shared__ float tile[CC * 129];
  __shared__ float pmax[2][128];
  const int t = threadIdx.x;
  const int half = blockIdx.x & 1, y = blockIdx.x >> 1, b = blockIdx.y;
  const int px0 = half * 128;
  const int pxl = t & 127, chb = (t >> 7) * 32;

  if (b == 0 && blockIdx.x < 18) {
    int gid = blockIdx.x * 256 + t;  // 4608 total
    int lane = gid & 63, kc = (gid >> 6) & 1, mt = (gid >> 7) & 3, tap = gid >> 9;
    int o = mt * 16 + (lane & 15);
    int kb = kc * 32 + (lane >> 4) * 8;
    int ky = tap / 3, kx = tap % 3;
    U16x8 r;
#pragma unroll
    for (int j = 0; j < 8; ++j)
      r.h[j] = f2bf(Wt[o * 576 + (kb + j) * 9 + ky * 3 + kx]);
    ((uint4*)Wp)[gid] = r.v;
  }

  const float* base = x + (size_t)b * CC * HH * WW + (size_t)y * WW + px0 + pxl;
  float m = -1e30f;
#pragma unroll 8
  for (int i = 0; i < 32; ++i) {
    float v = base[(size_t)(chb + i) * HH * WW];
    tile[(chb + i) * 129 + pxl] = v;
    m = fmaxf(m, v);
  }
  pmax[t >> 7][pxl] = m;

  uint4* xn4 = (uint4*)xn;
  if (t < 8) {
    int col = half ? (WP - 1) : 0;
    xn4[(((size_t)(b * HH + y) * WP + col) * CC + t * 8) >> 3] =
        make_uint4(0, 0, 0, 0);
  }
  __syncthreads();

  if (t < 128) {
    float mm = fmaxf(pmax[0][t], pmax[1][t]);
    s[(b * HH + y) * WW + px0 + t] = 25.0f / fminf(fmaxf(mm, 1.0f), 50.0f);
  }
#pragma unroll
  for (int g = 0; g < 4; ++g) {
    int px = g * 32 + (t >> 3), c8 = t & 7;
    U16x8 r;
#pragma unroll
    for (int j = 0; j < 8; ++j) r.h[j] = f2bf(tile[(c8 * 8 + j) * 129 + px]);
    xn4[(((size_t)(b * HH + y) * WP + px0 + px + 1) * CC + c8 * 8) >> 3] = r.v;
  }
}

// ---------------------------------------------------------------------------
// Conv tile (R6 body + R9 XCD swizzle; verified R10: FETCH at unique-data
// minimum). c2 layout [b][row+1][px][og] (uint2); LDS-transpose epilogue.
// ---------------------------------------------------------------------------
__global__ __launch_bounds__(256, 4) void k_lower(const unsigned short* __restrict__ xn,
                                                  const unsigned short* __restrict__ Wp,
                                                  const float* __restrict__ s,
                                                  unsigned short* __restrict__ c2) {
  __shared__ uint4 lds[2112];
  const int t = threadIdx.x;
  const int swz = ((int)blockIdx.x & 7) * 65 + ((int)blockIdx.x >> 3);
  if (swz >= 516) return;  // padding tiles (uniform per block)
  const int ctile = swz & 3, tr = swz >> 2;
  const int b = blockIdx.y;
  const int r0 = tr * 2 - 1;          // out rows r0, r0+1 in [-1, 256]
  const int colBase = ctile * 64;

  const uint4* xn4 = (const uint4*)xn;

  // ---- phase 1: all 9 per-thread s-loads in flight together
  float sva[9];
#pragma unroll
  for (int j = 0; j < 9; ++j) {
    int idx = j * 256 + t;
    bool act = (j < 8) || (t < 64);
    int rr_ = idx / 528, rem = idx % 528;
    int col_ = rem >> 3;
    int xrow = r0 - 1 + rr_;  // x2 row, [-2..258]
    bool va = act && (xrow >= 0) && (xrow < HH);
    int pxc = min(max(colBase + col_ - 1, 0), WW - 1);
    sva[j] = va ? s[(b * HH + min(max(xrow, 0), HH - 1)) * WW + pxc] : 0.0f;
  }

  // ---- phase 2: gather+blend in 5+4 batches (loads clustered per batch)
#pragma unroll
  for (int h = 0; h < 2; ++h) {
    const int jb = h * 5;
    const int n = h ? 4 : 5;
    uint4 u0[5], u1[5];
    float w0a[5], w1a[5];
    int la[5];
    bool act[5], va[5];
#pragma unroll
    for (int j = 0; j < 5; ++j) {
      if (j >= n) break;
      const int e = jb + j;
      int idx = e * 256 + t;
      act[j] = (e < 8) || (t < 64);
      int rr_ = idx / 528, rem = idx % 528;
      int col_ = rem >> 3, ch_ = rem & 7;
      int xrow = r0 - 1 + rr_;
      va[j] = act[j] && (xrow >= 0) && (xrow < HH);
      la[j] = (rr_ * 66 + col_) * 8 + (ch_ ^ (col_ & 7));
      float ys = (float)xrow - sva[e];
      float fy = floorf(ys);
      float wfr = ys - fy;
      int i0 = (int)fy;
      w0a[j] = (i0 >= 0) ? 1.0f - wfr : 0.0f;
      w1a[j] = (i0 + 1 >= 0) ? wfr : 0.0f;
      int a0 = min(max(i0, 0), HH - 1), a1 = min(max(i0 + 1, 0), HH - 1);
      int o0 = ((b * HH + a0) * WP + colBase + col_) * 8 + ch_;
      int o1 = ((b * HH + a1) * WP + colBase + col_) * 8 + ch_;
      if (va[j]) {
        u0[j] = xn4[o0];
        u1[j] = xn4[o1];
      }
    }
#pragma unroll
    for (int j = 0; j < 5; ++j) {
      if (j >= n) break;
      if (act[j]) {
        uint4 v = make_uint4(0, 0, 0, 0);
        if (va[j]) {
          U16x8 a, bb, rr;
          a.v = u0[j];
          bb.v = u1[j];
#pragma unroll
          for (int k = 0; k < 8; ++k)
            rr.h[k] = f2bf_trunc(w0a[j] * bf2f(a.h[k]) + w1a[j] * bf2f(bb.h[k]));
          v = rr.v;
        }
        lds[la[j]] = v;
      }
    }
  }

  const int lane = t & 63, w = t >> 6;
  const int ow = w & 1, ch2 = w >> 1;
  const int quad = lane >> 4, l15 = lane & 15;
  const uint4* wp4 = (const uint4*)Wp;
  __syncthreads();

  f32x4 acc[2][2][2];  // [pt][rr][ct]
#pragma unroll
  for (int pt = 0; pt < 2; ++pt)
#pragma unroll
    for (int rr = 0; rr < 2; ++rr)
#pragma unroll
      for (int ct = 0; ct < 2; ++ct) acc[pt][rr][ct] = {0.f, 0.f, 0.f, 0.f};

#pragma unroll 1
  for (int kc = 0; kc < 2; ++kc) {
    short8 wf[9][2];
#pragma unroll
    for (int tap = 0; tap < 9; ++tap)
#pragma unroll
      for (int ct = 0; ct < 2; ++ct)
        wf[tap][ct] = __builtin_bit_cast(
            short8, wp4[((tap * 4 + (ow * 2 + ct)) * 2 + kc) * 64 + lane]);
#pragma unroll
    for (int pt = 0; pt < 2; ++pt) {
#pragma unroll
      for (int ir = 0; ir < 4; ++ir) {
#pragma unroll
        for (int kx = 0; kx < 3; ++kx) {
          int col = ch2 * 32 + pt * 16 + l15 + kx;
          short8 xf = __builtin_bit_cast(
              short8, lds[(ir * 66 + col) * 8 + ((kc * 4 + quad) ^ (col & 7))]);
          if (ir <= 2) {
#pragma unroll
            for (int ct = 0; ct < 2; ++ct)
              acc[pt][0][ct] = MFMA_BF16(wf[ir * 3 + kx][ct], xf, acc[pt][0][ct], 0, 0, 0);
          }
          if (ir >= 1) {
#pragma unroll
            for (int ct = 0; ct < 2; ++ct)
              acc[pt][1][ct] = MFMA_BF16(wf[(ir - 1) * 3 + kx][ct], xf, acc[pt][1][ct], 0, 0, 0);
          }
        }
      }
    }
  }

  // ---- LDS-transpose epilogue: full-line c2 stores in [row][px][og] layout
  __syncthreads();  // all MFMA LDS reads complete before reuse
  uint2* sb = (uint2*)lds;  // [2][64] (row,px) units, stride 18 uint2 (16B-aligned)
#pragma unroll
  for (int pt = 0; pt < 2; ++pt) {
    int pxl = ch2 * 32 + pt * 16 + l15;  // block-local px 0..63
#pragma unroll
    for (int rr = 0; rr < 2; ++rr) {
#pragma unroll
      for (int ct = 0; ct < 2; ++ct) {
        f32x4 A = acc[pt][rr][ct];
        int og = (ow * 2 + ct) * 4 + quad;
        unsigned short h0 = f2bf(A[0]), h1 = f2bf(A[1]), h2 = f2bf(A[2]), h3 = f2bf(A[3]);
        sb[(rr * 64 + pxl) * 18 + og] =
            make_uint2((unsigned)h0 | ((unsigned)h1 << 16),
                       (unsigned)h2 | ((unsigned)h3 << 16));
      }
    }
  }
  __syncthreads();
  {
    uint2* c2u = (uint2*)c2;
    int h = t & 1, u = t >> 1;        // u = rr*64 + pxl
    int rr = u >> 6, pxl = u & 63;
    int r = r0 + rr;                  // r = -1 is REAL data (c2 row 0)
    if (r < 256) {
      const uint2* srcp = sb + u * 18 + h * 8;
      uint4 q0 = *(const uint4*)(srcp + 0);
      uint4 q1 = *(const uint4*)(srcp + 2);
      uint4 q2 = *(const uint4*)(srcp + 4);
      uint4 q3 = *(const uint4*)(srcp + 6);
      uint4* dst = (uint4*)(c2u + ((((size_t)(b * C2R + (r + 1)) * WW) + colBase + pxl) << 4) + h * 8);
      dst[0] = q0; dst[1] = q1; dst[2] = q2; dst[3] = q3;
    }
  }
}

// ---------------------------------------------------------------------------
// k_final (R10 exact: R6 body + XCD swizzle, NO gather hoist — R11's hoist
// spilled: VGPR stuck at 64, WRITE +8 MB, dur +2 µs). FETCH at unique-data
// minimum (33.9 MB), WRITE = out exactly (64 MiB), zero conflicts.
// ---------------------------------------------------------------------------
__global__ __launch_bounds__(256, 4) void k_final(const unsigned short* __restrict__ xn,
                                                  const unsigned short* __restrict__ Wp,
                                                  const float* __restrict__ s,
                                                  const unsigned short* __restrict__ c2,
                                                  float* __restrict__ out) {
  __shared__ uint4 lds[2112];
  const int t = threadIdx.x;
  const int swz = ((int)blockIdx.x & 7) * 64 + ((int)blockIdx.x >> 3);
  const int ctile = swz & 3, tr = swz >> 2;
  const int b = blockIdx.y;
  const int y0 = tr * 2;
  const int colBase = ctile * 64;

  const int lane = t & 63, w = t >> 6;
  const int ow = w & 1, ch2 = w >> 1;
  const int quad = lane >> 4, l15 = lane & 15;
  const uint4* src4 = (const uint4*)xn;
  const uint4* wp4 = (const uint4*)Wp;

  // hoisted epilogue s-loads: issue before staging, consumed after MFMA
  float sv_e[2][2];
#pragma unroll
  for (int pt = 0; pt < 2; ++pt)
#pragma unroll
    for (int rr = 0; rr < 2; ++rr)
      sv_e[pt][rr] =
          s[(b * HH + (y0 + rr)) * WW + (colBase + ch2 * 32 + pt * 16 + l15)];

  if (tr > 0 && tr < 127) {
    // fast path: 9 async direct-to-LDS loads per thread, all in flight
#pragma unroll
    for (int i = 0; i < 8; ++i) {
      int idx = i * 256 + t;
      int rr_ = idx / 528, rem = idx % 528;
      int col_ = rem >> 3, ch_ = rem & 7;
      int xrow = y0 - 1 + rr_;  // in [1,254], always valid here
      size_t srcIdx =
          ((size_t)(b * HH + xrow) * WP + colBase + col_) * 8 + (ch_ ^ (col_ & 7));
      __builtin_amdgcn_global_load_lds((gptr_t*)(const void*)(src4 + srcIdx),
                                       (lptr_t*)(void*)&lds[i * 256 + (t & 192)],
                                       16, 0, 0);
    }
    if (t < 64) {  // wave-uniform tail: elements 2048..2111
      int idx = 2048 + t;
      int rr_ = idx / 528, rem = idx % 528;
      int col_ = rem >> 3, ch_ = rem & 7;
      int xrow = y0 - 1 + rr_;
      size_t srcIdx =
          ((size_t)(b * HH + xrow) * WP + colBase + col_) * 8 + (ch_ ^ (col_ & 7));
      __builtin_amdgcn_global_load_lds((gptr_t*)(const void*)(src4 + srcIdx),
                                       (lptr_t*)(void*)&lds[2048],
                                       16, 0, 0);
    }
  } else {
    // boundary path: register staging with zero-fill
#pragma unroll
    for (int i = 0; i < 9; ++i) {
      int idx = i * 256 + t;
      if (idx < 2112) {
        int rr_ = idx / 528, rem = idx % 528;
        int col_ = rem >> 3, ch_ = rem & 7;
        int xrow = y0 - 1 + rr_;  // rows y0-1 .. y0+2
        uint4 v = make_uint4(0, 0, 0, 0);
        if (xrow >= 0 && xrow < HH)
          v = src4[((size_t)(b * HH + xrow) * WP + colBase + col_) * 8 + ch_];
        lds[(rr_ * 66 + col_) * 8 + (ch_ ^ (col_ & 7))] = v;
      }
    }
  }
  __syncthreads();

  f32x4 acc[2][2][2];
#pragma unroll
  for (int pt = 0; pt < 2; ++pt)
#pragma unroll
    for (int rr = 0; rr < 2; ++rr)
#pragma unroll
      for (int ct = 0; ct < 2; ++ct) acc[pt][rr][ct] = {0.f, 0.f, 0.f, 0.f};

#pragma unroll 1
  for (int kc = 0; kc < 2; ++kc) {
    short8 wf[9][2];
#pragma unroll
    for (int tap = 0; tap < 9; ++tap)
#pragma unroll
      for (int ct = 0; ct < 2; ++ct)
        wf[tap][ct] = __builtin_bit_cast(
            short8, wp4[((tap * 4 + (ow * 2 + ct)) * 2 + kc) * 64 + lane]);
#pragma unroll
    for (int pt = 0; pt < 2; ++pt) {
#pragma unroll
      for (int ir = 0; ir < 4; ++ir) {
#pragma unroll
        for (int kx = 0; kx < 3; ++kx) {
          int col = ch2 * 32 + pt * 16 + l15 + kx;
          short8 xf = __builtin_bit_cast(
              short8, lds[(ir * 66 + col) * 8 + ((kc * 4 + quad) ^ (col & 7))]);
          if (ir <= 2) {
#pragma unroll
            for (int ct = 0; ct < 2; ++ct)
              acc[pt][0][ct] = MFMA_BF16(wf[ir * 3 + kx][ct], xf, acc[pt][0][ct], 0, 0, 0);
          }
          if (ir >= 1) {
#pragma unroll
            for (int ct = 0; ct < 2; ++ct)
              acc[pt][1][ct] = MFMA_BF16(wf[(ir - 1) * 3 + kx][ct], xf, acc[pt][1][ct], 0, 0, 0);
          }
        }
      }
    }
  }

  // ---- epilogue: gather + min into LDS (fp32), then full-line out stores
  __syncthreads();             // MFMA LDS reads complete; reuse buffer
  float* lf = (float*)lds;     // 128 units (u=rr*64+c) x 64 dwords = 32 KB
  const uint2* c2u = (const uint2*)c2;
#pragma unroll
  for (int pt = 0; pt < 2; ++pt) {
    int pxl = ch2 * 32 + pt * 16 + l15;
    int px = colBase + pxl;
#pragma unroll
    for (int rr = 0; rr < 2; ++rr) {
      int y = y0 + rr;
      float sv = sv_e[pt][rr];
      float ys = (float)y - sv;
      float fy = floorf(ys);
      float wfr = ys - fy;
      int i0 = (int)fy;
      float lw0 = (i0 + 1 >= 0 && i0 + 1 <= HH) ? 1.0f - wfr : 0.0f;
      float lw1 = (i0 + 2 >= 0 && i0 + 2 <= HH) ? wfr : 0.0f;
      int a0 = min(max(i0 + 1, 0), HH);
      int a1 = min(max(i0 + 2, 0), HH);
#pragma unroll
      for (int ct = 0; ct < 2; ++ct) {
        f32x4 A = acc[pt][rr][ct];
        int og = (ow * 2 + ct) * 4 + quad;
        U16x4 v0, v1;
        // c2 layout: [b][row][px][og]
        v0.v = c2u[(((size_t)(b * C2R + a0) * WW + px) << 4) + og];
        v1.v = c2u[(((size_t)(b * C2R + a1) * WW + px) << 4) + og];
#pragma unroll
        for (int reg = 0; reg < 4; ++reg) {
          float lower = lw0 * bf2f(v0.h[reg]) + lw1 * bf2f(v1.h[reg]);
          int u = rr * 64 + og * 4 + reg;
          // 4-dword XOR swizzle keeps write 2-way-bank-free and read 16B-aligned
          lf[u * 64 + (((pxl >> 2) ^ (u & 15)) << 2) + (pxl & 3)] =
              fminf(A[reg], lower);
        }
      }
    }
  }
  __syncthreads();
#pragma unroll
  for (int j = 0; j < 8; ++j) {
    int u = w * 32 + j * 4 + (lane >> 4);   // wave covers units [32w, 32w+32)
    int c = u & 63, rr = u >> 6;
    int lp = lane & 15;
    const float* srcp = lf + u * 64 + ((lp ^ (u & 15)) << 2);
    float4 q = *(const float4*)srcp;
    *(float4*)(out + ((size_t)(b * CC + c) * HH + (y0 + rr)) * WW + colBase +
               lp * 4) = q;
  }
}

// ---------------------------------------------------------------------------
extern "C" void kernel_launch(void* const* d_in, const int* in_sizes, int n_in,
                              void* d_out, int out_size, void* d_ws, size_t ws_size,
                              hipStream_t stream) {
  const float* x = (const float*)d_in[0];
  const float* Wt = (const float*)d_in[1];
  float* out = (float*)d_out;

  char* ws = (char*)d_ws;
  float* s = (float*)ws;                                   //   1,048,576 B
  unsigned short* Wp = (unsigned short*)(ws + 1048576);    //      73,728 B
  unsigned short* xn = (unsigned short*)(ws + 1122304);    //  33,816,576 B
  unsigned short* c2 = (unsigned short*)(ws + 34938880);   //  33,685,504 B
                                                           // total 68.6 MB
  k_pack<<<dim3(HH * 2, BB), 256, 0, stream>>>(x, Wt, s, xn, Wp);
  k_lower<<<dim3(520, BB), 256, 0, stream>>>(xn, Wp, s, c2);    // 520 = 8*65 (4 pad tiles)
  k_final<<<dim3(512, BB), 256, 0, stream>>>(xn, Wp, s, c2, out);
}